// Round 1
// baseline (78.182 us; speedup 1.0000x reference)
//
#include <hip/hip_runtime.h>

// ===========================================================================
// Exact algebraic reduction (verified rounds 2-4, absmax <= 1 bf16 ulp):
//   ev_q(b) = e0_q + (e1_q - e0_q) * Podd(b)
//   Podd(b) = 0.5*(1 - cos(t0+W00)cos(t1+W01)cos(t2+W02))
//   e0/e1 from two 512-dim sims (psi0 = V|chi>, psi1 = V X^x9 |chi>).
// Amp bits 0..2 = register (qubits 9,10,11), bits 3..8 = lane (qubits 3..8).
//
// Round-6 changes (latency attack; residual ~30us over the 39.6us harness
// poison-fill floor is a serial shfl/VALU chain with 2/4 waves idle):
//  1. DUAL-STATE sim: every wave computes BOTH psi0 and psi1 interleaved in
//     registers. Two independent chains -> shfl latencies overlap; all 4
//     waves busy; no wave specialization.
//  2. eS LDS buffer + trailing __syncthreads removed: each wave broadcasts
//     its own 18 observables via parallel __shfl (depth 1 stage).
//  3. WHT butterfly fused with the 3 reg-bit reductions into ONE float4
//     butterfly: reduction depth 12 shfl stages -> 6.
// ===========================================================================

typedef float2 cplx;
__device__ inline cplx cmul(cplx a, cplx b) {
  return make_float2(a.x * b.x - a.y * b.y, a.x * b.y + a.y * b.x);
}
__device__ inline cplx cshfl_xor(cplx v, int m) {
  return make_float2(__shfl_xor(v.x, m, 64), __shfl_xor(v.y, m, 64));
}

// --- dual-state RY(thy) then RZ(thz) on bit-position BP (0..8) -------------
template <int BP>
__device__ inline void rot_gate(cplx (&A)[8], cplx (&D)[8], float c, float s,
                                float cz, float sz) {
  if constexpr (BP < 3) {  // register qubit
    constexpr int m = 1 << BP;
#pragma unroll
    for (int r = 0; r < 8; r++)
      if (!(r & m)) {
        const int r1 = r | m;
        {
          const cplx a0 = A[r], a1 = A[r1];
          const float n0x = c * a0.x - s * a1.x, n0y = c * a0.y - s * a1.y;
          const float n1x = s * a0.x + c * a1.x, n1y = s * a0.y + c * a1.y;
          A[r] = make_float2(cz * n0x + sz * n0y, cz * n0y - sz * n0x);
          A[r1] = make_float2(cz * n1x - sz * n1y, cz * n1y + sz * n1x);
        }
        {
          const cplx a0 = D[r], a1 = D[r1];
          const float n0x = c * a0.x - s * a1.x, n0y = c * a0.y - s * a1.y;
          const float n1x = s * a0.x + c * a1.x, n1y = s * a0.y + c * a1.y;
          D[r] = make_float2(cz * n0x + sz * n0y, cz * n0y - sz * n0x);
          D[r1] = make_float2(cz * n1x - sz * n1y, cz * n1y + sz * n1x);
        }
      }
  } else {  // lane qubit (bit of tid == bit of lane for shifts <= 5)
    constexpr int lm = 1 << (BP - 3);
    const int bit = (threadIdx.x >> (BP - 3)) & 1;
    const float sy = bit ? s : -s;
    const float so = bit ? -sz : sz;
#pragma unroll
    for (int r = 0; r < 8; r++) {
      const cplx pA = cshfl_xor(A[r], lm);
      const cplx pD = cshfl_xor(D[r], lm);
      const float nxA = c * A[r].x + sy * pA.x, nyA = c * A[r].y + sy * pA.y;
      A[r] = make_float2(cz * nxA + so * nyA, cz * nyA - so * nxA);
      const float nxD = c * D[r].x + sy * pD.x, nyD = c * D[r].y + sy * pD.y;
      D[r] = make_float2(cz * nxD + so * nyD, cz * nyD - so * nxD);
    }
  }
}

// --- dual-state general SU(2) gate (fused RY*RZ*RY layer) ------------------
template <int BP>
__device__ inline void su2_gate(cplx (&A)[8], cplx (&D)[8], cplx u00, cplx u01,
                                cplx u10, cplx u11) {
  if constexpr (BP < 3) {
    constexpr int m = 1 << BP;
#pragma unroll
    for (int r = 0; r < 8; r++)
      if (!(r & m)) {
        const int r1 = r | m;
        {
          const cplx a0 = A[r], a1 = A[r1];
          const cplx t0 = cmul(u00, a0), t1 = cmul(u01, a1);
          const cplx t2 = cmul(u10, a0), t3 = cmul(u11, a1);
          A[r] = make_float2(t0.x + t1.x, t0.y + t1.y);
          A[r1] = make_float2(t2.x + t3.x, t2.y + t3.y);
        }
        {
          const cplx a0 = D[r], a1 = D[r1];
          const cplx t0 = cmul(u00, a0), t1 = cmul(u01, a1);
          const cplx t2 = cmul(u10, a0), t3 = cmul(u11, a1);
          D[r] = make_float2(t0.x + t1.x, t0.y + t1.y);
          D[r1] = make_float2(t2.x + t3.x, t2.y + t3.y);
        }
      }
  } else {
    constexpr int lm = 1 << (BP - 3);
    const int bit = (threadIdx.x >> (BP - 3)) & 1;
    const cplx uA = bit ? u11 : u00;
    const cplx uB = bit ? u10 : u01;
#pragma unroll
    for (int r = 0; r < 8; r++) {
      const cplx pA = cshfl_xor(A[r], lm);
      const cplx pD = cshfl_xor(D[r], lm);
      {
        const cplx t0 = cmul(uA, A[r]), t1 = cmul(uB, pA);
        A[r] = make_float2(t0.x + t1.x, t0.y + t1.y);
      }
      {
        const cplx t0 = cmul(uA, D[r]), t1 = cmul(uB, pD);
        D[r] = make_float2(t0.x + t1.x, t0.y + t1.y);
      }
    }
  }
}

// --- dual-state CNOTs by operand location ----------------------------------
template <int CB, int TB>
__device__ inline void cnot_rr(cplx (&A)[8], cplx (&D)[8]) {
#pragma unroll
  for (int r = 0; r < 8; r++)
    if ((r & (1 << CB)) && !(r & (1 << TB))) {
      const int r1 = r | (1 << TB);
      const cplx tA = A[r];
      A[r] = A[r1];
      A[r1] = tA;
      const cplx tD = D[r];
      D[r] = D[r1];
      D[r1] = tD;
    }
}
template <int CB, int TL>
__device__ inline void cnot_rl(cplx (&A)[8], cplx (&D)[8]) {
#pragma unroll
  for (int r = 0; r < 8; r++)
    if (r & (1 << CB)) {
      A[r] = cshfl_xor(A[r], 1 << TL);
      D[r] = cshfl_xor(D[r], 1 << TL);
    }
}
template <int CL, int TB>
__device__ inline void cnot_lr(cplx (&A)[8], cplx (&D)[8]) {
  const bool c = (threadIdx.x >> CL) & 1;
#pragma unroll
  for (int r = 0; r < 8; r++)
    if (!(r & (1 << TB))) {
      const int r1 = r | (1 << TB);
      {
        const cplx t0 = A[r];
        A[r] = c ? A[r1] : A[r];
        A[r1] = c ? t0 : A[r1];
      }
      {
        const cplx t0 = D[r];
        D[r] = c ? D[r1] : D[r];
        D[r1] = c ? t0 : D[r1];
      }
    }
}
template <int CL, int TL>
__device__ inline void cnot_ll(cplx (&A)[8], cplx (&D)[8]) {
  const bool c = (threadIdx.x >> CL) & 1;
#pragma unroll
  for (int r = 0; r < 8; r++) {
    const cplx pA = cshfl_xor(A[r], 1 << TL);
    A[r] = c ? pA : A[r];
    const cplx pD = cshfl_xor(D[r], 1 << TL);
    D[r] = c ? pD : D[r];
  }
}

// ===========================================================================
__global__ __launch_bounds__(256) void qnpe_fused(
    const float* __restrict__ cov, const float* __restrict__ dose,
    const float* __restrict__ w, const float* __restrict__ pkb,
    const float* __restrict__ pdb, float* __restrict__ out, int B) {
  __shared__ float csn[2][108];  // cos/sin of 0.5*w[i]
  __shared__ cplx F[9][2];       // per-qubit init factors (layer 0/1 on |0>)
  __shared__ cplx G[2][8];       // reg-qubit init products, per flip-state s
  __shared__ cplx Ug[9][4];      // fused layer-678 SU(2): u00,u01,u10,u11

  const int tid = threadIdx.x;
  const int b = blockIdx.x * 256 + tid;

  // hoist batch loads above the sim chain (latency overlap)
  float x0 = 0.f, x1 = 0.f, x2 = 0.f;
  if (b < B) {
    x0 = cov[2 * b];
    x1 = cov[2 * b + 1];
    x2 = dose[b];
  }
  const float w0 = w[0], w1 = w[1], w2 = w[2];

  if (tid < 108) {
    float s, c;
    __sincosf(0.5f * w[tid], &s, &c);
    csn[0][tid] = c;
    csn[1][tid] = s;
  }
  __syncthreads();

  if (tid < 9) {  // F_q: RZ(W1)*RY(W0)|0> factors, qubit 3+tid
    const float c0 = csn[0][3 + tid], s0 = csn[1][3 + tid];
    const float cz = csn[0][12 + 3 + tid], sz = csn[1][12 + 3 + tid];
    F[tid][0] = make_float2(c0 * cz, -c0 * sz);
    F[tid][1] = make_float2(s0 * cz, s0 * sz);
  } else if (tid >= 16 && tid < 25) {  // fused U = RY(w8)*RZ(w7)*RY(w6)
    const int q = tid - 16;
    const float c6 = csn[0][6 * 12 + 3 + q], s6 = csn[1][6 * 12 + 3 + q];
    const float c7 = csn[0][7 * 12 + 3 + q], s7 = csn[1][7 * 12 + 3 + q];
    const float c8 = csn[0][8 * 12 + 3 + q], s8 = csn[1][8 * 12 + 3 + q];
    const cplx em = make_float2(c7, -s7), ep = make_float2(c7, s7);
    const cplx M00 = make_float2(c6 * em.x, c6 * em.y);
    const cplx M01 = make_float2(-s6 * em.x, -s6 * em.y);
    const cplx M10 = make_float2(s6 * ep.x, s6 * ep.y);
    const cplx M11 = make_float2(c6 * ep.x, c6 * ep.y);
    Ug[q][0] = make_float2(c8 * M00.x - s8 * M10.x, c8 * M00.y - s8 * M10.y);
    Ug[q][1] = make_float2(c8 * M01.x - s8 * M11.x, c8 * M01.y - s8 * M11.y);
    Ug[q][2] = make_float2(s8 * M00.x + c8 * M10.x, s8 * M00.y + c8 * M10.y);
    Ug[q][3] = make_float2(s8 * M01.x + c8 * M11.x, s8 * M01.y + c8 * M11.y);
  }
  __syncthreads();

  if (tid < 16) {  // reg-qubit init products (qubits 9,10,11 = F[6..8])
    const int s = tid >> 3, r = tid & 7;
    cplx g = cmul(F[6][((r >> 2) & 1) ^ s], F[7][((r >> 1) & 1) ^ s]);
    G[s][r] = cmul(g, F[8][(r & 1) ^ s]);
  }
  __syncthreads();

  // ---- every wave simulates BOTH psi0 and psi1 (interleaved chains) ----
  const int lane = tid & 63;
  cplx a0s[8], a1s[8];
  {
    // product-state init over lane qubits (3..8 -> lane bits 5..0)
    cplx P0 = F[0][(lane >> 5) & 1];
    cplx P1 = F[0][((lane >> 5) & 1) ^ 1];
    P0 = cmul(P0, F[1][(lane >> 4) & 1]);
    P1 = cmul(P1, F[1][((lane >> 4) & 1) ^ 1]);
    P0 = cmul(P0, F[2][(lane >> 3) & 1]);
    P1 = cmul(P1, F[2][((lane >> 3) & 1) ^ 1]);
    P0 = cmul(P0, F[3][(lane >> 2) & 1]);
    P1 = cmul(P1, F[3][((lane >> 2) & 1) ^ 1]);
    P0 = cmul(P0, F[4][(lane >> 1) & 1]);
    P1 = cmul(P1, F[4][((lane >> 1) & 1) ^ 1]);
    P0 = cmul(P0, F[5][lane & 1]);
    P1 = cmul(P1, F[5][(lane & 1) ^ 1]);
#pragma unroll
    for (int r = 0; r < 8; r++) {
      a0s[r] = cmul(P0, G[0][r]);
      a1s[r] = cmul(P1, G[1][r]);
    }
  }

#define ROTQ(Q, BP, LY, LZ)                                                \
  rot_gate<BP>(a0s, a1s, csn[0][(LY)*12 + (Q)], csn[1][(LY)*12 + (Q)],     \
               csn[0][(LZ)*12 + (Q)], csn[1][(LZ)*12 + (Q)]);
  // rot layer W2/W3
  ROTQ(3, 8, 2, 3) ROTQ(4, 7, 2, 3) ROTQ(5, 6, 2, 3)
  ROTQ(6, 5, 2, 3) ROTQ(7, 4, 2, 3) ROTQ(8, 3, 2, 3)
  ROTQ(9, 2, 2, 3) ROTQ(10, 1, 2, 3) ROTQ(11, 0, 2, 3)
  // pk ring (3,4)(4,5)(5,6)(6,7)(7,3)
  cnot_ll<5, 4>(a0s, a1s);
  cnot_ll<4, 3>(a0s, a1s);
  cnot_ll<3, 2>(a0s, a1s);
  cnot_ll<2, 1>(a0s, a1s);
  cnot_ll<1, 5>(a0s, a1s);
  // pd ring (8,9)(9,10)(10,11)(11,8)
  cnot_lr<0, 2>(a0s, a1s);
  cnot_rr<2, 1>(a0s, a1s);
  cnot_rr<1, 0>(a0s, a1s);
  cnot_rl<0, 0>(a0s, a1s);
  // rot layer W4/W5
  ROTQ(3, 8, 4, 5) ROTQ(4, 7, 4, 5) ROTQ(5, 6, 4, 5)
  ROTQ(6, 5, 4, 5) ROTQ(7, 4, 4, 5) ROTQ(8, 3, 4, 5)
  ROTQ(9, 2, 4, 5) ROTQ(10, 1, 4, 5) ROTQ(11, 0, 4, 5)
#undef ROTQ
  // cross (3,8)(4,9)(5,10)(6,11)(7,8)
  cnot_ll<5, 0>(a0s, a1s);
  cnot_lr<4, 2>(a0s, a1s);
  cnot_lr<3, 1>(a0s, a1s);
  cnot_lr<2, 0>(a0s, a1s);
  cnot_ll<1, 0>(a0s, a1s);
  // fused layer W6/W7/W8
  su2_gate<8>(a0s, a1s, Ug[0][0], Ug[0][1], Ug[0][2], Ug[0][3]);
  su2_gate<7>(a0s, a1s, Ug[1][0], Ug[1][1], Ug[1][2], Ug[1][3]);
  su2_gate<6>(a0s, a1s, Ug[2][0], Ug[2][1], Ug[2][2], Ug[2][3]);
  su2_gate<5>(a0s, a1s, Ug[3][0], Ug[3][1], Ug[3][2], Ug[3][3]);
  su2_gate<4>(a0s, a1s, Ug[4][0], Ug[4][1], Ug[4][2], Ug[4][3]);
  su2_gate<3>(a0s, a1s, Ug[5][0], Ug[5][1], Ug[5][2], Ug[5][3]);
  su2_gate<2>(a0s, a1s, Ug[6][0], Ug[6][1], Ug[6][2], Ug[6][3]);
  su2_gate<1>(a0s, a1s, Ug[7][0], Ug[7][1], Ug[7][2], Ug[7][3]);
  su2_gate<0>(a0s, a1s, Ug[8][0], Ug[8][1], Ug[8][2], Ug[8][3]);

  // ---- measurement: one fused float4 WHT butterfly per state ----
  // pack (tot, v6, v7, v8); after 6 levels lane L holds
  // sum_l (-1)^{popc(l&L)} x_l. Lane-obs q at L = 32>>q (tot comp);
  // reg-obs 6/7/8 at L = 0 (v6/v7/v8 comps = plain sums).
  float4 m0, m1;
  {
    float p0[8], p1[8];
    float t0 = 0.f, t1 = 0.f;
#pragma unroll
    for (int r = 0; r < 8; r++) {
      p0[r] = a0s[r].x * a0s[r].x + a0s[r].y * a0s[r].y;
      t0 += p0[r];
      p1[r] = a1s[r].x * a1s[r].x + a1s[r].y * a1s[r].y;
      t1 += p1[r];
    }
    float v60 = 0.f, v70 = 0.f, v80 = 0.f, v61 = 0.f, v71 = 0.f, v81 = 0.f;
#pragma unroll
    for (int r = 0; r < 8; r++) {
      v60 += ((r >> 2) & 1) ? -p0[r] : p0[r];
      v70 += ((r >> 1) & 1) ? -p0[r] : p0[r];
      v80 += (r & 1) ? -p0[r] : p0[r];
      v61 += ((r >> 2) & 1) ? -p1[r] : p1[r];
      v71 += ((r >> 1) & 1) ? -p1[r] : p1[r];
      v81 += (r & 1) ? -p1[r] : p1[r];
    }
    m0 = make_float4(t0, v60, v70, v80);
    m1 = make_float4(t1, v61, v71, v81);
  }
#pragma unroll
  for (int k = 0; k < 6; k++) {
    const int msk = 1 << k;
    const float q0x = __shfl_xor(m0.x, msk, 64);
    const float q0y = __shfl_xor(m0.y, msk, 64);
    const float q0z = __shfl_xor(m0.z, msk, 64);
    const float q0w = __shfl_xor(m0.w, msk, 64);
    const float q1x = __shfl_xor(m1.x, msk, 64);
    const float q1y = __shfl_xor(m1.y, msk, 64);
    const float q1z = __shfl_xor(m1.z, msk, 64);
    const float q1w = __shfl_xor(m1.w, msk, 64);
    const bool hi = (lane >> k) & 1;
    m0.x = hi ? (q0x - m0.x) : (m0.x + q0x);
    m0.y = hi ? (q0y - m0.y) : (m0.y + q0y);
    m0.z = hi ? (q0z - m0.z) : (m0.z + q0z);
    m0.w = hi ? (q0w - m0.w) : (m0.w + q0w);
    m1.x = hi ? (q1x - m1.x) : (m1.x + q1x);
    m1.y = hi ? (q1y - m1.y) : (m1.y + q1y);
    m1.z = hi ? (q1z - m1.z) : (m1.z + q1z);
    m1.w = hi ? (q1w - m1.w) : (m1.w + q1w);
  }

  // broadcast observables within the wave (18 independent shfls, depth 1)
  const float E0[9] = {__shfl(m0.x, 32, 64), __shfl(m0.x, 16, 64),
                       __shfl(m0.x, 8, 64),  __shfl(m0.x, 4, 64),
                       __shfl(m0.x, 2, 64),  __shfl(m0.x, 1, 64),
                       __shfl(m0.y, 0, 64),  __shfl(m0.z, 0, 64),
                       __shfl(m0.w, 0, 64)};
  const float E1[9] = {__shfl(m1.x, 32, 64), __shfl(m1.x, 16, 64),
                       __shfl(m1.x, 8, 64),  __shfl(m1.x, 4, 64),
                       __shfl(m1.x, 2, 64),  __shfl(m1.x, 1, 64),
                       __shfl(m1.y, 0, 64),  __shfl(m1.z, 0, 64),
                       __shfl(m1.w, 0, 64)};

  if (b >= B) return;
  const float g = __cosf(x0 + w0) * __cosf(x1 + w1) * __cosf(x2 + w2);
  const float podd = 0.5f * (1.f - g);

#pragma unroll
  for (int q = 0; q < 9; q++) {
    const float e = E0[q] + (E1[q] - E0[q]) * podd;
    const float norm = 0.5f * (e + 1.f);
    if (q < 5) {
      out[b * 5 + q] = pkb[2 * q] + norm * (pkb[2 * q + 1] - pkb[2 * q]);
    } else {
      const int j = q - 5;
      out[B * 5 + b * 4 + j] =
          pdb[2 * j] + norm * (pdb[2 * j + 1] - pdb[2 * j]);
    }
  }
}

// ===========================================================================
extern "C" void kernel_launch(void* const* d_in, const int* in_sizes, int n_in,
                              void* d_out, int out_size, void* d_ws,
                              size_t ws_size, hipStream_t stream) {
  // inputs: 0 subject_ids (unused), 1 covariates (B,2) f32, 2 dose (B,) f32,
  //         3 weights (108,) f32, 4 pk_bounds (5,2) f32, 5 pd_bounds (4,2) f32
  const float* cov = (const float*)d_in[1];
  const float* dose = (const float*)d_in[2];
  const float* wts = (const float*)d_in[3];
  const float* pkb = (const float*)d_in[4];
  const float* pdb = (const float*)d_in[5];
  float* out = (float*)d_out;
  const int B = in_sizes[2];

  hipLaunchKernelGGL(qnpe_fused, dim3((B + 255) / 256), dim3(256), 0, stream,
                     cov, dose, wts, pkb, pdb, out, B);
}

// Round 2
// 71.824 us; speedup vs baseline: 1.0885x; 1.0885x over previous
//
#include <hip/hip_runtime.h>

// ===========================================================================
// Exact algebraic reduction (verified rounds 2-4, absmax <= 1 bf16 ulp):
//   ev_q(b) = e0_q + (e1_q - e0_q) * Podd(b)
//   Podd(b) = 0.5*(1 - cos(t0+W00)cos(t1+W01)cos(t2+W02))
//   e0/e1 from two 512-dim sims (psi0 = V|chi>, psi1 = V X^x9 |chi>).
// Sims live in one wave's registers: 8 complex amps/lane; amp bits 0..2 =
// register (qubits 9,10,11), bits 3..8 = lane (qubits 3..8).
//
// Round-7: revert round-6 dual-state regression (78us; doubled DS/VALU issue
// count per wave, 4x redundant work). Back to round-0 wave-specialized
// structure (71us verified), keeping round-6's one structural win:
//   measurement = ONE float4 WHT butterfly carrying (tot, v6, v7, v8)
//   -> 6 serial shfl stages instead of 6 (WHT) + 6 (reg-obs reduction).
// ===========================================================================

typedef float2 cplx;
__device__ inline cplx cmul(cplx a, cplx b) {
  return make_float2(a.x * b.x - a.y * b.y, a.x * b.y + a.y * b.x);
}
__device__ inline cplx cshfl_xor(cplx v, int m) {
  return make_float2(__shfl_xor(v.x, m, 64), __shfl_xor(v.y, m, 64));
}

// --- RY(thy) then RZ(thz) on bit-position BP (0..8) ------------------------
template <int BP>
__device__ inline void rot_gate(cplx (&a)[8], float c, float s, float cz,
                                float sz) {
  if constexpr (BP < 3) {  // register qubit
    constexpr int m = 1 << BP;
#pragma unroll
    for (int r = 0; r < 8; r++)
      if (!(r & m)) {
        const int r1 = r | m;
        const cplx a0 = a[r], a1 = a[r1];
        const float n0x = c * a0.x - s * a1.x, n0y = c * a0.y - s * a1.y;
        const float n1x = s * a0.x + c * a1.x, n1y = s * a0.y + c * a1.y;
        a[r] = make_float2(cz * n0x + sz * n0y, cz * n0y - sz * n0x);
        a[r1] = make_float2(cz * n1x - sz * n1y, cz * n1y + sz * n1x);
      }
  } else {  // lane qubit
    constexpr int lm = 1 << (BP - 3);
    const int bit = (threadIdx.x >> (BP - 3)) & 1;
    const float sy = bit ? s : -s;
    const float so = bit ? -sz : sz;
#pragma unroll
    for (int r = 0; r < 8; r++) {
      const cplx p = cshfl_xor(a[r], lm);
      const float nx = c * a[r].x + sy * p.x, ny = c * a[r].y + sy * p.y;
      a[r] = make_float2(cz * nx + so * ny, cz * ny - so * nx);
    }
  }
}

// --- general SU(2) gate (fused RY*RZ*RY layer) -----------------------------
template <int BP>
__device__ inline void su2_gate(cplx (&a)[8], cplx u00, cplx u01, cplx u10,
                                cplx u11) {
  if constexpr (BP < 3) {
    constexpr int m = 1 << BP;
#pragma unroll
    for (int r = 0; r < 8; r++)
      if (!(r & m)) {
        const int r1 = r | m;
        const cplx a0 = a[r], a1 = a[r1];
        const cplx t0 = cmul(u00, a0), t1 = cmul(u01, a1);
        const cplx t2 = cmul(u10, a0), t3 = cmul(u11, a1);
        a[r] = make_float2(t0.x + t1.x, t0.y + t1.y);
        a[r1] = make_float2(t2.x + t3.x, t2.y + t3.y);
      }
  } else {
    constexpr int lm = 1 << (BP - 3);
    const int bit = (threadIdx.x >> (BP - 3)) & 1;
    const cplx uA = bit ? u11 : u00;
    const cplx uB = bit ? u10 : u01;
#pragma unroll
    for (int r = 0; r < 8; r++) {
      const cplx p = cshfl_xor(a[r], lm);
      const cplx t0 = cmul(uA, a[r]), t1 = cmul(uB, p);
      a[r] = make_float2(t0.x + t1.x, t0.y + t1.y);
    }
  }
}

// --- CNOTs by operand location ---------------------------------------------
template <int CB, int TB>
__device__ inline void cnot_rr(cplx (&a)[8]) {
#pragma unroll
  for (int r = 0; r < 8; r++)
    if ((r & (1 << CB)) && !(r & (1 << TB))) {
      const int r1 = r | (1 << TB);
      const cplx t = a[r];
      a[r] = a[r1];
      a[r1] = t;
    }
}
template <int CB, int TL>
__device__ inline void cnot_rl(cplx (&a)[8]) {
#pragma unroll
  for (int r = 0; r < 8; r++)
    if (r & (1 << CB)) a[r] = cshfl_xor(a[r], 1 << TL);
}
template <int CL, int TB>
__device__ inline void cnot_lr(cplx (&a)[8]) {
  const bool c = (threadIdx.x >> CL) & 1;
#pragma unroll
  for (int r = 0; r < 8; r++)
    if (!(r & (1 << TB))) {
      const int r1 = r | (1 << TB);
      const cplx t0 = a[r];
      a[r] = c ? a[r1] : a[r];
      a[r1] = c ? t0 : a[r1];
    }
}
template <int CL, int TL>
__device__ inline void cnot_ll(cplx (&a)[8]) {
  const bool c = (threadIdx.x >> CL) & 1;
#pragma unroll
  for (int r = 0; r < 8; r++) {
    const cplx p = cshfl_xor(a[r], 1 << TL);
    a[r] = c ? p : a[r];
  }
}

// ===========================================================================
__global__ __launch_bounds__(256) void qnpe_fused(
    const float* __restrict__ cov, const float* __restrict__ dose,
    const float* __restrict__ w, const float* __restrict__ pkb,
    const float* __restrict__ pdb, float* __restrict__ out, int B) {
  __shared__ float csn[2][108];  // cos/sin of 0.5*w[i]
  __shared__ cplx F[9][2];       // per-qubit init factors (layer 0/1 on |0>)
  __shared__ cplx G[2][8];       // reg-qubit init products, per flip-state s
  __shared__ cplx Ug[9][4];      // fused layer-678 SU(2): u00,u01,u10,u11
  __shared__ float eS[2][9];

  const int tid = threadIdx.x;
  const int b = blockIdx.x * 256 + tid;

  // hoist batch loads above the sim chain (latency overlap)
  float x0 = 0.f, x1 = 0.f, x2 = 0.f;
  if (b < B) {
    x0 = cov[2 * b];
    x1 = cov[2 * b + 1];
    x2 = dose[b];
  }
  const float w0 = w[0], w1 = w[1], w2 = w[2];

  if (tid < 108) {
    float s, c;
    __sincosf(0.5f * w[tid], &s, &c);
    csn[0][tid] = c;
    csn[1][tid] = s;
  }
  __syncthreads();

  if (tid < 9) {  // F_q: RZ(W1)*RY(W0)|0> factors, qubit 3+tid
    const float c0 = csn[0][3 + tid], s0 = csn[1][3 + tid];
    const float cz = csn[0][12 + 3 + tid], sz = csn[1][12 + 3 + tid];
    F[tid][0] = make_float2(c0 * cz, -c0 * sz);
    F[tid][1] = make_float2(s0 * cz, s0 * sz);
  } else if (tid >= 16 && tid < 25) {  // fused U = RY(w8)*RZ(w7)*RY(w6)
    const int q = tid - 16;
    const float c6 = csn[0][6 * 12 + 3 + q], s6 = csn[1][6 * 12 + 3 + q];
    const float c7 = csn[0][7 * 12 + 3 + q], s7 = csn[1][7 * 12 + 3 + q];
    const float c8 = csn[0][8 * 12 + 3 + q], s8 = csn[1][8 * 12 + 3 + q];
    const cplx em = make_float2(c7, -s7), ep = make_float2(c7, s7);
    const cplx M00 = make_float2(c6 * em.x, c6 * em.y);
    const cplx M01 = make_float2(-s6 * em.x, -s6 * em.y);
    const cplx M10 = make_float2(s6 * ep.x, s6 * ep.y);
    const cplx M11 = make_float2(c6 * ep.x, c6 * ep.y);
    Ug[q][0] = make_float2(c8 * M00.x - s8 * M10.x, c8 * M00.y - s8 * M10.y);
    Ug[q][1] = make_float2(c8 * M01.x - s8 * M11.x, c8 * M01.y - s8 * M11.y);
    Ug[q][2] = make_float2(s8 * M00.x + c8 * M10.x, s8 * M00.y + c8 * M10.y);
    Ug[q][3] = make_float2(s8 * M01.x + c8 * M11.x, s8 * M01.y + c8 * M11.y);
  }
  __syncthreads();

  if (tid < 16) {  // reg-qubit init products (qubits 9,10,11 = F[6..8])
    const int s = tid >> 3, r = tid & 7;
    cplx g = cmul(F[6][((r >> 2) & 1) ^ s], F[7][((r >> 1) & 1) ^ s]);
    G[s][r] = cmul(g, F[8][(r & 1) ^ s]);
  }
  __syncthreads();

  const int wave = tid >> 6;
  if (wave < 2) {  // wave s simulates psi_s
    const int lane = tid & 63;
    const int s = wave;
    cplx a[8];
    // product-state init: P over lane qubits (3..8 -> lane bits 5..0)
    cplx P = F[0][((lane >> 5) & 1) ^ s];
    P = cmul(P, F[1][((lane >> 4) & 1) ^ s]);
    P = cmul(P, F[2][((lane >> 3) & 1) ^ s]);
    P = cmul(P, F[3][((lane >> 2) & 1) ^ s]);
    P = cmul(P, F[4][((lane >> 1) & 1) ^ s]);
    P = cmul(P, F[5][(lane & 1) ^ s]);
#pragma unroll
    for (int r = 0; r < 8; r++) a[r] = cmul(P, G[s][r]);

#define ROTQ(Q, BP, LY, LZ)                                               \
  rot_gate<BP>(a, csn[0][(LY)*12 + (Q)], csn[1][(LY)*12 + (Q)],           \
               csn[0][(LZ)*12 + (Q)], csn[1][(LZ)*12 + (Q)]);
    // rot layer W2/W3
    ROTQ(3, 8, 2, 3) ROTQ(4, 7, 2, 3) ROTQ(5, 6, 2, 3)
    ROTQ(6, 5, 2, 3) ROTQ(7, 4, 2, 3) ROTQ(8, 3, 2, 3)
    ROTQ(9, 2, 2, 3) ROTQ(10, 1, 2, 3) ROTQ(11, 0, 2, 3)
    // pk ring (3,4)(4,5)(5,6)(6,7)(7,3)
    cnot_ll<5, 4>(a);
    cnot_ll<4, 3>(a);
    cnot_ll<3, 2>(a);
    cnot_ll<2, 1>(a);
    cnot_ll<1, 5>(a);
    // pd ring (8,9)(9,10)(10,11)(11,8)
    cnot_lr<0, 2>(a);
    cnot_rr<2, 1>(a);
    cnot_rr<1, 0>(a);
    cnot_rl<0, 0>(a);
    // rot layer W4/W5
    ROTQ(3, 8, 4, 5) ROTQ(4, 7, 4, 5) ROTQ(5, 6, 4, 5)
    ROTQ(6, 5, 4, 5) ROTQ(7, 4, 4, 5) ROTQ(8, 3, 4, 5)
    ROTQ(9, 2, 4, 5) ROTQ(10, 1, 4, 5) ROTQ(11, 0, 4, 5)
#undef ROTQ
    // cross (3,8)(4,9)(5,10)(6,11)(7,8)
    cnot_ll<5, 0>(a);
    cnot_lr<4, 2>(a);
    cnot_lr<3, 1>(a);
    cnot_lr<2, 0>(a);
    cnot_ll<1, 0>(a);
    // fused layer W6/W7/W8
    su2_gate<8>(a, Ug[0][0], Ug[0][1], Ug[0][2], Ug[0][3]);
    su2_gate<7>(a, Ug[1][0], Ug[1][1], Ug[1][2], Ug[1][3]);
    su2_gate<6>(a, Ug[2][0], Ug[2][1], Ug[2][2], Ug[2][3]);
    su2_gate<5>(a, Ug[3][0], Ug[3][1], Ug[3][2], Ug[3][3]);
    su2_gate<4>(a, Ug[4][0], Ug[4][1], Ug[4][2], Ug[4][3]);
    su2_gate<3>(a, Ug[5][0], Ug[5][1], Ug[5][2], Ug[5][3]);
    su2_gate<2>(a, Ug[6][0], Ug[6][1], Ug[6][2], Ug[6][3]);
    su2_gate<1>(a, Ug[7][0], Ug[7][1], Ug[7][2], Ug[7][3]);
    su2_gate<0>(a, Ug[8][0], Ug[8][1], Ug[8][2], Ug[8][3]);

    // ---- measurement: one fused float4 WHT butterfly ----
    // pack (tot, v6, v7, v8); after 6 levels lane L holds
    // sum_l (-1)^{popc(l&L)} x_l for each component. Lane-obs q reads the
    // tot component at L = 32>>q; reg-obs 6/7/8 read y/z/w at L = 0
    // (plain sums). 6 serial stages instead of 6 (WHT) + 6 (reg reduce).
    float4 m;
    {
      float p[8], tot = 0.f;
#pragma unroll
      for (int r = 0; r < 8; r++) {
        p[r] = a[r].x * a[r].x + a[r].y * a[r].y;
        tot += p[r];
      }
      float v6 = 0.f, v7 = 0.f, v8 = 0.f;
#pragma unroll
      for (int r = 0; r < 8; r++) {
        v6 += ((r >> 2) & 1) ? -p[r] : p[r];
        v7 += ((r >> 1) & 1) ? -p[r] : p[r];
        v8 += (r & 1) ? -p[r] : p[r];
      }
      m = make_float4(tot, v6, v7, v8);
    }
#pragma unroll
    for (int k = 0; k < 6; k++) {
      const int msk = 1 << k;
      const float qx = __shfl_xor(m.x, msk, 64);
      const float qy = __shfl_xor(m.y, msk, 64);
      const float qz = __shfl_xor(m.z, msk, 64);
      const float qw = __shfl_xor(m.w, msk, 64);
      const bool hi = (lane >> k) & 1;
      m.x = hi ? (qx - m.x) : (m.x + qx);
      m.y = hi ? (qy - m.y) : (m.y + qy);
      m.z = hi ? (qz - m.z) : (m.z + qz);
      m.w = hi ? (qw - m.w) : (m.w + qw);
    }
    // obs ob (0..5) measures lane bit 5-ob -> WHT index 32>>ob
    if (lane == 32) eS[s][0] = m.x;
    if (lane == 16) eS[s][1] = m.x;
    if (lane == 8) eS[s][2] = m.x;
    if (lane == 4) eS[s][3] = m.x;
    if (lane == 2) eS[s][4] = m.x;
    if (lane == 1) eS[s][5] = m.x;
    if (lane == 0) {
      eS[s][6] = m.y;
      eS[s][7] = m.z;
      eS[s][8] = m.w;
    }
  }
  __syncthreads();

  if (b >= B) return;
  const float g = __cosf(x0 + w0) * __cosf(x1 + w1) * __cosf(x2 + w2);
  const float podd = 0.5f * (1.f - g);

#pragma unroll
  for (int q = 0; q < 9; q++) {
    const float e = eS[0][q] + (eS[1][q] - eS[0][q]) * podd;
    const float norm = 0.5f * (e + 1.f);
    if (q < 5) {
      out[b * 5 + q] = pkb[2 * q] + norm * (pkb[2 * q + 1] - pkb[2 * q]);
    } else {
      const int j = q - 5;
      out[B * 5 + b * 4 + j] =
          pdb[2 * j] + norm * (pdb[2 * j + 1] - pdb[2 * j]);
    }
  }
}

// ===========================================================================
extern "C" void kernel_launch(void* const* d_in, const int* in_sizes, int n_in,
                              void* d_out, int out_size, void* d_ws,
                              size_t ws_size, hipStream_t stream) {
  // inputs: 0 subject_ids (unused), 1 covariates (B,2) f32, 2 dose (B,) f32,
  //         3 weights (108,) f32, 4 pk_bounds (5,2) f32, 5 pd_bounds (4,2) f32
  const float* cov = (const float*)d_in[1];
  const float* dose = (const float*)d_in[2];
  const float* wts = (const float*)d_in[3];
  const float* pkb = (const float*)d_in[4];
  const float* pdb = (const float*)d_in[5];
  float* out = (float*)d_out;
  const int B = in_sizes[2];

  hipLaunchKernelGGL(qnpe_fused, dim3((B + 255) / 256), dim3(256), 0, stream,
                     cov, dose, wts, pkb, pdb, out, B);
}